// Round 6
// baseline (4799.314 us; speedup 1.0000x reference)
//
#include <hip/hip_runtime.h>
#include <hip/hip_fp16.h>
#include <stdint.h>

#define NB 32
#define NT 2048
#define ND 256
#define NU 256

typedef _Float16 f16x2 __attribute__((ext_vector_type(2)));

__device__ __forceinline__ float fdot2u(uint32_t a, uint32_t b, float c) {
#if __has_builtin(__builtin_amdgcn_fdot2)
  return __builtin_amdgcn_fdot2(__builtin_bit_cast(f16x2, a),
                                __builtin_bit_cast(f16x2, b), c, false);
#else
  f16x2 av = __builtin_bit_cast(f16x2, a);
  f16x2 bv = __builtin_bit_cast(f16x2, b);
  return c + (float)av.x * (float)bv.x + (float)av.y * (float)bv.y;
#endif
}

__device__ __forceinline__ uint32_t packh2(float lo, float hi) {
  f16x2 p;
  p.x = (_Float16)lo;
  p.y = (_Float16)hi;
  return __builtin_bit_cast(uint32_t, p);
}

__device__ __forceinline__ float rcp_fast(float x) { return __builtin_amdgcn_rcpf(x); }
__device__ __forceinline__ float sigmoid_fast(float x) {
  return rcp_fast(1.f + __expf(-x));
}
__device__ __forceinline__ float tanh_fast(float x) {
  return 1.f - 2.f * rcp_fast(1.f + __expf(2.f * x));
}

// Per-thread weight footprint: 3 gates x 64 K-elems = 192 f16 = 96 VGPRs.
// Total regs ~118 < 128 (the hard cap for a 1024-thread block = 16 waves =
// 4 waves/SIMD). R1-R5 showed the allocator enforces a 128-reg budget and
// remats/spills anything above it; this design fits under it.
struct SRec {
  float hbuf[NU];
  alignas(16) uint32_t h2[NU / 2];
  alignas(16) uint32_t rh2[NU / 2];
  float psA[4][2][NU];  // [q][z|r][u]
  float psH[4][NU];     // [q][u]
};
struct SGemm {
  float a[64][132];  // [k][m], padded
  float b[64][68];   // [k][n], padded
};

// One kernel, two roles by blockIdx:
//  blocks [0, recCnt) : GRU recurrence for chunk [t0r, t0r+chunkT), one batch each
//  blocks [recCnt, .) : fp32 GEMM computing x-projections for chunk starting t0g
__global__ __launch_bounds__(1024) void gru_combined(
    const float* __restrict__ x, const float* __restrict__ Wz,
    const float* __restrict__ Wr, const float* __restrict__ Wh,
    const uint32_t* __restrict__ Wf16, float* __restrict__ hstate,
    float* __restrict__ out, const float* __restrict__ Gsrc,
    float* __restrict__ Gdst, int t0r, int t0g, int recCnt, int chunkT) {
  __shared__ union SM {
    SRec r;
    SGemm g;
  } sm;
  const int tid = threadIdx.x;

  if ((int)blockIdx.x < recCnt) {
    // ---------------- recurrence ----------------
    const int b = blockIdx.x;
    const int u = tid & (NU - 1);
    const int q = tid >> 8;  // K-quarter 0..3

    // weights: 8 uint4 per gate per thread; layout Wp[((g*4+q)*8+j)*256+u]
    // (lane-consecutive u -> perfectly coalesced 16B loads)
    uint4 wz[8], wr[8], wh[8];
    const uint4* W4 = (const uint4*)Wf16;
#pragma unroll
    for (int j = 0; j < 8; j++) wz[j] = W4[((0 * 4 + q) * 8 + j) * 256 + u];
#pragma unroll
    for (int j = 0; j < 8; j++) wr[j] = W4[((1 * 4 + q) * 8 + j) * 256 + u];
#pragma unroll
    for (int j = 0; j < 8; j++) wh[j] = W4[((2 * 4 + q) * 8 + j) * 256 + u];

    const float hs = hstate[b * NU + u];  // all q-groups load (same value per u)
    if (tid < NU) sm.r.hbuf[tid] = hs;
    __syncthreads();
    if (tid < NU / 2)
      sm.r.h2[tid] = packh2(sm.r.hbuf[2 * tid], sm.r.hbuf[2 * tid + 1]);
    __syncthreads();
    float hcur = hs;  // live in q0 for the blend

    const float* Gb = Gsrc + (size_t)b * NU + u;
    float* outp = out + ((size_t)b * NT + t0r) * NU + u;

    // G prefetch for t=0 (q0: gz,gh ; q1: gr)
    float cgz = 0.f, cgr = 0.f, cgh = 0.f;
    if (q == 0) {
      cgz = Gb[0];
      cgh = Gb[2 * NB * NU];
    } else if (q == 1) {
      cgr = Gb[NB * NU];
    }

    for (int tt = 0; tt < chunkT; ++tt) {
      // prefetch next step's x-projections (hidden under phase-A dots)
      float ngz = 0.f, ngr = 0.f, ngh = 0.f;
      {
        const int tn = (tt + 1 < chunkT) ? tt + 1 : tt;
        const float* Gt = Gb + (size_t)(tn * 3) * NB * NU;
        if (q == 0) {
          ngz = Gt[0];
          ngh = Gt[2 * NB * NU];
        } else if (q == 1) {
          ngr = Gt[NB * NU];
        }
      }
      // phase A: z and r partial dots over this thread's K-quarter
      float az0 = 0.f, az1 = 0.f, ar0 = 0.f, ar1 = 0.f;
#pragma unroll
      for (int jb = 0; jb < 8; jb++) {
        uint4 hv = *(const uint4*)&sm.r.h2[q * 32 + jb * 4];
        az0 = fdot2u(wz[jb].x, hv.x, az0);
        az1 = fdot2u(wz[jb].y, hv.y, az1);
        az0 = fdot2u(wz[jb].z, hv.z, az0);
        az1 = fdot2u(wz[jb].w, hv.w, az1);
        ar0 = fdot2u(wr[jb].x, hv.x, ar0);
        ar1 = fdot2u(wr[jb].y, hv.y, ar1);
        ar0 = fdot2u(wr[jb].z, hv.z, ar0);
        ar1 = fdot2u(wr[jb].w, hv.w, ar1);
      }
      sm.r.psA[q][0][u] = az0 + az1;
      sm.r.psA[q][1][u] = ar0 + ar1;
      __syncthreads();  // b1: psA ready
      float zval = 0.f;
      if (q == 0) {
        zval = sigmoid_fast(cgz + ((sm.r.psA[0][0][u] + sm.r.psA[1][0][u]) +
                                   (sm.r.psA[2][0][u] + sm.r.psA[3][0][u])));
      } else if (q == 1) {
        const float rr =
            sigmoid_fast(cgr + ((sm.r.psA[0][1][u] + sm.r.psA[1][1][u]) +
                                (sm.r.psA[2][1][u] + sm.r.psA[3][1][u])));
        const float rh = rr * sm.r.hbuf[u];
        const float rh1 = __shfl_down(rh, 1);
        if ((u & 1) == 0) sm.r.rh2[u >> 1] = packh2(rh, rh1);
      }
      __syncthreads();  // b2: rh2 ready
      // phase B: h_hat partial dot over this thread's K-quarter
      float ah0 = 0.f, ah1 = 0.f;
#pragma unroll
      for (int jb = 0; jb < 8; jb++) {
        uint4 rv = *(const uint4*)&sm.r.rh2[q * 32 + jb * 4];
        ah0 = fdot2u(wh[jb].x, rv.x, ah0);
        ah1 = fdot2u(wh[jb].y, rv.y, ah1);
        ah0 = fdot2u(wh[jb].z, rv.z, ah0);
        ah1 = fdot2u(wh[jb].w, rv.w, ah1);
      }
      sm.r.psH[q][u] = ah0 + ah1;
      __syncthreads();  // b3: psH ready
      if (q == 0) {
        const float hh = tanh_fast(cgh + ((sm.r.psH[0][u] + sm.r.psH[1][u]) +
                                          (sm.r.psH[2][u] + sm.r.psH[3][u])));
        const float hn = zval * hcur + (1.f - zval) * hh;
        hcur = hn;
        outp[0] = hn;
        sm.r.hbuf[u] = hn;
        const float hn1 = __shfl_down(hn, 1);
        if ((u & 1) == 0) sm.r.h2[u >> 1] = packh2(hn, hn1);
      }
      outp += NU;
      cgz = ngz;
      cgr = ngr;
      cgh = ngh;
      __syncthreads();  // b4: h2/hbuf ready for next step
    }
    if (q == 0) hstate[b * NU + u] = hcur;

  } else if (Gdst != nullptr) {
    // ---------------- x-projection GEMM for next chunk ----------------
    // C[M=32*chunkT, N=768] = X[M,256]*W[256,768]; tile 128x64, 1024 thr, 2x4 micro
    const int gg = (int)blockIdx.x - recCnt;
    const int mtile = gg / 12;
    const int ntile = gg - mtile * 12;
    const int g = ntile >> 2;
    const int u0 = (ntile & 3) * 64;
    const float* Wg = (g == 0) ? Wz : ((g == 1) ? Wr : Wh);
    const int tx = tid & 15;   // 0..15 -> col group of 4
    const int ty = tid >> 4;   // 0..63 -> row group of 2
    const int mbase = mtile * 128;
    float acc[2][4] = {{0.f}};

    for (int kk = 0; kk < 4; ++kk) {
      const int k0 = kk * 64;
      __syncthreads();
      {  // A tile: 128 rows x 64 k, stored transposed [k][m]
        const int ml = tid & 127;
        const int kq = tid >> 7;  // 0..7, 8 k-elems each
        const int m = mbase + ml;
        const int bb = m / chunkT;
        const int ttm = m - bb * chunkT;
        const float* xp = x + ((size_t)bb * NT + t0g + ttm) * ND + k0 + kq * 8;
        const float4 x0 = ((const float4*)xp)[0];
        const float4 x1 = ((const float4*)xp)[1];
        sm.g.a[kq * 8 + 0][ml] = x0.x;
        sm.g.a[kq * 8 + 1][ml] = x0.y;
        sm.g.a[kq * 8 + 2][ml] = x0.z;
        sm.g.a[kq * 8 + 3][ml] = x0.w;
        sm.g.a[kq * 8 + 4][ml] = x1.x;
        sm.g.a[kq * 8 + 5][ml] = x1.y;
        sm.g.a[kq * 8 + 6][ml] = x1.z;
        sm.g.a[kq * 8 + 7][ml] = x1.w;
      }
      {  // B tile: 64 k x 64 n (ty doubles as k-row 0..63)
        const float4 wv = *(const float4*)&Wg[(size_t)(k0 + ty) * NU + u0 + tx * 4];
        *(float4*)&sm.g.b[ty][tx * 4] = wv;
      }
      __syncthreads();
#pragma unroll 8
      for (int k = 0; k < 64; ++k) {
        const float2 av = *(const float2*)&sm.g.a[k][ty * 2];
        const float4 bv = *(const float4*)&sm.g.b[k][tx * 4];
        acc[0][0] += av.x * bv.x; acc[0][1] += av.x * bv.y;
        acc[0][2] += av.x * bv.z; acc[0][3] += av.x * bv.w;
        acc[1][0] += av.y * bv.x; acc[1][1] += av.y * bv.y;
        acc[1][2] += av.y * bv.z; acc[1][3] += av.y * bv.w;
      }
    }
    // epilogue: G[tt][gate][b][u]
#pragma unroll
    for (int i = 0; i < 2; ++i) {
      const int m = mbase + ty * 2 + i;
      const int bb = m / chunkT;
      const int ttm = m - bb * chunkT;
      float4 val;
      val.x = acc[i][0]; val.y = acc[i][1]; val.z = acc[i][2]; val.w = acc[i][3];
      *(float4*)&Gdst[((size_t)(ttm * 3 + g) * NB + bb) * NU + u0 + tx * 4] = val;
    }
  }
}

// one-time prep: pack recurrent weight rows [D, D+U) into f16 pairs with the
// [((g*4+q)*8+j)*256+u] uint4 layout; zero h state
__global__ void gru_prep(const float* __restrict__ Wz, const float* __restrict__ Wr,
                         const float* __restrict__ Wh, uint32_t* __restrict__ Wf16,
                         float* __restrict__ hstate) {
  const int idx = blockIdx.x * 256 + threadIdx.x;
  const int NW = 3 * 4 * 8 * 256 * 4;  // 98304 u32
  if (idx < NW) {
    const int c = idx & 3;
    const int u = (idx >> 2) & 255;
    const int j = (idx >> 10) & 7;
    const int q = (idx >> 13) & 3;
    const int g = idx >> 15;
    const float* Wg = (g == 0) ? Wz : ((g == 1) ? Wr : Wh);
    const int k = 64 * q + 8 * j + 2 * c;
    const float w0 = Wg[(size_t)(ND + k) * NU + u];
    const float w1 = Wg[(size_t)(ND + k + 1) * NU + u];
    Wf16[idx] = packh2(w0, w1);
  } else if (idx - NW < NB * NU) {
    hstate[idx - NW] = 0.f;
  }
}

extern "C" void kernel_launch(void* const* d_in, const int* in_sizes, int n_in,
                              void* d_out, int out_size, void* d_ws, size_t ws_size,
                              hipStream_t stream) {
  (void)in_sizes; (void)n_in; (void)out_size;
  const float* x = (const float*)d_in[0];
  const float* Wz = (const float*)d_in[1];
  const float* Wr = (const float*)d_in[2];
  const float* Wh = (const float*)d_in[3];
  float* out = (float*)d_out;

  // pick largest chunk that fits ws: 2 G buffers + Wf16 + hstate
  int ct = 8;
  const int cands[6] = {256, 128, 64, 32, 16, 8};
  for (int i = 0; i < 6; ++i) {
    size_t need = 2ull * cands[i] * 3 * NB * NU * 4 + (1u << 20);
    if (need <= ws_size) { ct = cands[i]; break; }
  }
  const int nch = NT / ct;
  const size_t chunkBytes = (size_t)ct * 3 * NB * NU * 4;

  char* wsb = (char*)d_ws;
  float* G0 = (float*)wsb;
  float* G1 = (float*)(wsb + chunkBytes);
  uint32_t* Wf16 = (uint32_t*)(wsb + 2 * chunkBytes);
  float* hstate = (float*)(wsb + 2 * chunkBytes + (size_t)3 * NU * 128 * 4);

  const int prepThreads = 3 * 4 * 8 * 256 * 4 + NB * NU;
  gru_prep<<<(prepThreads + 255) / 256, 256, 0, stream>>>(Wz, Wr, Wh, Wf16, hstate);

  // chunk 0 x-projection only
  gru_combined<<<3 * ct, 1024, 0, stream>>>(x, Wz, Wr, Wh, Wf16, hstate, out,
                                            nullptr, G0, 0, 0, 0, ct);
  for (int k = 0; k < nch; ++k) {
    float* Gsrc = (k & 1) ? G1 : G0;
    float* Gdst = (k & 1) ? G0 : G1;
    const int gemmOn = (k + 1 < nch) ? 1 : 0;
    gru_combined<<<32 + (gemmOn ? 3 * ct : 0), 1024, 0, stream>>>(
        x, Wz, Wr, Wh, Wf16, hstate, out, Gsrc, gemmOn ? Gdst : nullptr,
        k * ct, (k + 1) * ct, 32, ct);
  }
}

// Round 7
// 4681.626 us; speedup vs baseline: 1.0251x; 1.0251x over previous
//
#include <hip/hip_runtime.h>
#include <hip/hip_fp16.h>
#include <stdint.h>

#define NB 32
#define NT 2048
#define ND 256
#define NU 256

typedef unsigned long long u64;
typedef _Float16 f16x2 __attribute__((ext_vector_type(2)));

__device__ __forceinline__ float fdot2u(uint32_t a, uint32_t b, float c) {
#if __has_builtin(__builtin_amdgcn_fdot2)
  return __builtin_amdgcn_fdot2(__builtin_bit_cast(f16x2, a),
                                __builtin_bit_cast(f16x2, b), c, false);
#else
  f16x2 av = __builtin_bit_cast(f16x2, a);
  f16x2 bv = __builtin_bit_cast(f16x2, b);
  return c + (float)av.x * (float)bv.x + (float)av.y * (float)bv.y;
#endif
}

__device__ __forceinline__ uint32_t packh2(float lo, float hi) {
  f16x2 p;
  p.x = (_Float16)lo;
  p.y = (_Float16)hi;
  return __builtin_bit_cast(uint32_t, p);
}

__device__ __forceinline__ float rcp_fast(float x) { return __builtin_amdgcn_rcpf(x); }
__device__ __forceinline__ float sigmoid_fast(float x) {
  return rcp_fast(1.f + __expf(-x));
}
__device__ __forceinline__ float tanh_fast(float x) {
  return 1.f - 2.f * rcp_fast(1.f + __expf(2.f * x));
}

// ---------------- one-time prep ----------------
// Packs recurrent weight rows [D, D+U) as f16 pairs in per-(slice,gate,kq,u_l)
// layout: u32 index w = (((s*3+g)*8+kq)*32 + u_l)*16 + p, k = kq*32+2p,
// u = s*32+u_l. Also zeroes the exchange buffers (ticks restart each launch).
__global__ void gru_prep(const float* __restrict__ Wz, const float* __restrict__ Wr,
                         const float* __restrict__ Wh, uint32_t* __restrict__ Wp,
                         uint32_t* __restrict__ exch_u32) {
  const int idx = blockIdx.x * 256 + threadIdx.x;
  const int NWP = 3 * 8 * 8 * 32 * 16;  // 98304 u32
  if (idx < NWP) {
    const int p = idx & 15;
    const int u_l = (idx >> 4) & 31;
    const int kq = (idx >> 9) & 7;
    const int t3 = idx >> 12;  // s*3+g, 0..23
    const int g = t3 % 3, s = t3 / 3;
    const float* Wg = (g == 0) ? Wz : ((g == 1) ? Wr : Wh);
    const int k = kq * 32 + 2 * p;
    const int u = s * 32 + u_l;
    Wp[idx] = packh2(Wg[(size_t)(ND + k) * NU + u], Wg[(size_t)(ND + k + 1) * NU + u]);
  } else if (idx - NWP < 16384) {
    exch_u32[idx - NWP] = 0u;  // 8192 u64 = exchA + exchB
  }
}

// ---------------- x-projection GEMM (fp32, f16 output) ----------------
// C[M=NB*nt, N=768] = X[M,256] * W[:256, 768]; tile 128x64, 512 thr, 4x4 micro.
struct SGemm {
  float a[64][132];  // [k][m], padded
  float b[64][68];   // [k][n], padded
};

__global__ __launch_bounds__(512) void gru_gemm(
    const float* __restrict__ x, const float* __restrict__ Wz,
    const float* __restrict__ Wr, const float* __restrict__ Wh,
    __half* __restrict__ Gh, int t0, int nt) {
  __shared__ SGemm sm;
  const int tid = threadIdx.x;
  const int gg = (int)blockIdx.x;
  const int mtile = gg / 12;
  const int ntile = gg - mtile * 12;
  const int g = ntile >> 2;
  const int u0 = (ntile & 3) * 64;
  const float* Wg = (g == 0) ? Wz : ((g == 1) ? Wr : Wh);
  const int ty = tid >> 4;  // 0..31
  const int tx = tid & 15;  // 0..15
  const int mbase = mtile * 128;
  float acc[4][4] = {{0.f}};

  for (int kk = 0; kk < 4; ++kk) {
    const int k0 = kk * 64;
    __syncthreads();
    {  // A tile: 128 rows x 64 k, store transposed [k][m]
      const int ml = tid & 127;
      const int kq = tid >> 7;  // 0..3
      const int m = mbase + ml;
      const int bb = m / nt;
      const int ttm = m - bb * nt;
      const float* xp = x + ((size_t)bb * NT + t0 + ttm) * ND + k0 + kq * 16;
#pragma unroll
      for (int v = 0; v < 4; ++v) {
        float4 xv = ((const float4*)xp)[v];
        sm.a[kq * 16 + v * 4 + 0][ml] = xv.x;
        sm.a[kq * 16 + v * 4 + 1][ml] = xv.y;
        sm.a[kq * 16 + v * 4 + 2][ml] = xv.z;
        sm.a[kq * 16 + v * 4 + 3][ml] = xv.w;
      }
    }
    {  // B tile: 64 k x 64 n
      const int nl = (tid & 15) * 4;
      const int kr = tid >> 4;  // 0..31
#pragma unroll
      for (int s2 = 0; s2 < 2; ++s2) {
        const int krow = kr + s2 * 32;
        float4 wv = *(const float4*)&Wg[(size_t)(k0 + krow) * NU + u0 + nl];
        *(float4*)&sm.b[krow][nl] = wv;
      }
    }
    __syncthreads();
#pragma unroll 8
    for (int k = 0; k < 64; ++k) {
      const float4 av = *(const float4*)&sm.a[k][ty * 4];
      const float4 bv = *(const float4*)&sm.b[k][tx * 4];
      acc[0][0] += av.x * bv.x; acc[0][1] += av.x * bv.y; acc[0][2] += av.x * bv.z; acc[0][3] += av.x * bv.w;
      acc[1][0] += av.y * bv.x; acc[1][1] += av.y * bv.y; acc[1][2] += av.y * bv.z; acc[1][3] += av.y * bv.w;
      acc[2][0] += av.z * bv.x; acc[2][1] += av.z * bv.y; acc[2][2] += av.z * bv.z; acc[2][3] += av.z * bv.w;
      acc[3][0] += av.w * bv.x; acc[3][1] += av.w * bv.y; acc[3][2] += av.w * bv.z; acc[3][3] += av.w * bv.w;
    }
  }
  // epilogue: Gh[ttm][gate][bb][u] as f16
#pragma unroll
  for (int i = 0; i < 4; ++i) {
    const int m = mbase + ty * 4 + i;
    const int bb = m / nt;
    const int ttm = m - bb * nt;
    uint2 o;
    o.x = packh2(acc[i][0], acc[i][1]);
    o.y = packh2(acc[i][2], acc[i][3]);
    *(uint2*)&Gh[((size_t)(ttm * 3 + g) * NB + bb) * NU + u0 + tx * 4] = o;
  }
}

// ---------------- persistent recurrence ----------------
// 256 blocks = 32 batches x 8 U-slices; block (bb,s) owns u in [32s, 32s+32).
// 256 threads: u_l = tid&31, kq = tid>>5 (K-slice of 32). Per-thread weights:
// 3 gates x 4 uint4 = 48 VGPRs. Cross-block exchange of rh/h slices via
// single-u64 {tick,data} agent-scope atomics (no fences needed: payload and
// flag are one atomic word). Two rounds per step; tick = 2*gt+1 / 2*gt+2 is
// monotonic so buffers need zeroing only once per launch (gru_prep).
__global__ __launch_bounds__(256)
__attribute__((amdgpu_waves_per_eu(1, 4)))
void gru_rec(const uint32_t* __restrict__ Wp, const __half* __restrict__ Gh,
             float* __restrict__ out, u64* exch, float* __restrict__ hstate,
             int t0, int nt, int init) {
  const int bid = (int)blockIdx.x;
  // siblings of a batch share bid%8 (likely same XCD; correct regardless)
  const int bb = (bid & 7) + 8 * (bid >> 6);
  const int s = (bid >> 3) & 7;
  const int tid = threadIdx.x;
  const int u_l = tid & 31;
  const int kq = tid >> 5;
  const int u = s * 32 + u_l;

  uint4 wz[4], wr[4], wh[4];
  {
    const uint4* W4 = (const uint4*)Wp;
    const int b0 = (s * 3 + 0) * 1024 + kq * 128 + u_l * 4;
    const int b1 = (s * 3 + 1) * 1024 + kq * 128 + u_l * 4;
    const int b2 = (s * 3 + 2) * 1024 + kq * 128 + u_l * 4;
#pragma unroll
    for (int j = 0; j < 4; j++) {
      wz[j] = W4[b0 + j];
      wr[j] = W4[b1 + j];
      wh[j] = W4[b2 + j];
    }
  }

  __shared__ uint32_t h2full[128], rh2full[128];
  __shared__ float psZ[8][32], psR[8][32], psH[8][32];
  __shared__ float zbuf[32], hown[32];

  u64* exA = exch + ((size_t)bb * 8 + s) * 16;
  u64* exB = exch + 4096 + ((size_t)bb * 8 + s) * 16;

  if (init) {
    if (tid < 128) h2full[tid] = 0u;
    if (tid < 32) hown[tid] = 0.f;
  } else {
    if (tid < 128)
      h2full[tid] = packh2(hstate[bb * NU + 2 * tid], hstate[bb * NU + 2 * tid + 1]);
    if (tid < 32) hown[tid] = hstate[bb * NU + s * 32 + tid];
  }
  __syncthreads();

  float cgz = 0.f, cgr = 0.f, cgh = 0.f, ngz = 0.f, ngr = 0.f, ngh = 0.f;
  if (tid < 32) {
    cgz = (float)Gh[((size_t)0 * NB + bb) * NU + u];
    cgr = (float)Gh[((size_t)1 * NB + bb) * NU + u];
    cgh = (float)Gh[((size_t)2 * NB + bb) * NU + u];
  }

  for (int tt = 0; tt < nt; ++tt) {
    const int gt = t0 + tt;
    const uint32_t tickA = 2u * (uint32_t)gt + 1u;
    const uint32_t tickB = tickA + 1u;

    // phase A: z/r partial dots over this thread's K-slice
    float a0 = 0.f, a1 = 0.f, r0 = 0.f, r1 = 0.f;
#pragma unroll
    for (int j = 0; j < 4; j++) {
      const uint4 hv = *(const uint4*)&h2full[kq * 16 + j * 4];
      a0 = fdot2u(wz[j].x, hv.x, a0);
      a1 = fdot2u(wz[j].y, hv.y, a1);
      a0 = fdot2u(wz[j].z, hv.z, a0);
      a1 = fdot2u(wz[j].w, hv.w, a1);
      r0 = fdot2u(wr[j].x, hv.x, r0);
      r1 = fdot2u(wr[j].y, hv.y, r1);
      r0 = fdot2u(wr[j].z, hv.z, r0);
      r1 = fdot2u(wr[j].w, hv.w, r1);
    }
    psZ[kq][u_l] = a0 + a1;
    psR[kq][u_l] = r0 + r1;
    __syncthreads();
    if (tid < 32) {
      float sz = cgz, sr = cgr;
#pragma unroll
      for (int k = 0; k < 8; k++) {
        sz += psZ[k][tid];
        sr += psR[k][tid];
      }
      const float z = sigmoid_fast(sz);
      const float r = sigmoid_fast(sr);
      zbuf[tid] = z;
      const float rh = r * hown[tid];
      const float rhn = __shfl_down(rh, 1);
      if ((tid & 1) == 0) {
        const uint32_t pk = packh2(rh, rhn);
        rh2full[s * 16 + (tid >> 1)] = pk;
        __hip_atomic_store(&exA[tid >> 1], ((u64)tickA << 32) | pk,
                           __ATOMIC_RELAXED, __HIP_MEMORY_SCOPE_AGENT);
      }
      // prefetch next-step G (in flight across phase B + spins)
      const int tl = (tt + 1 < nt) ? tt + 1 : tt;
      ngz = (float)Gh[((size_t)(tl * 3 + 0) * NB + bb) * NU + u];
      ngr = (float)Gh[((size_t)(tl * 3 + 1) * NB + bb) * NU + u];
      ngh = (float)Gh[((size_t)(tl * 3 + 2) * NB + bb) * NU + u];
    }
    __syncthreads();
    // gather siblings' rh slices
    if (tid < 128) {
      const int which = tid >> 4, w = tid & 15;
      if (which != s) {
        const u64* p = exch + ((size_t)bb * 8 + which) * 16 + w;
        u64 v;
        do {
          v = __hip_atomic_load(p, __ATOMIC_RELAXED, __HIP_MEMORY_SCOPE_AGENT);
        } while ((uint32_t)(v >> 32) < tickA);
        rh2full[which * 16 + w] = (uint32_t)v;
      }
    }
    __syncthreads();
    // phase B: h_hat partial dots
    float h0 = 0.f, h1 = 0.f;
#pragma unroll
    for (int j = 0; j < 4; j++) {
      const uint4 rv = *(const uint4*)&rh2full[kq * 16 + j * 4];
      h0 = fdot2u(wh[j].x, rv.x, h0);
      h1 = fdot2u(wh[j].y, rv.y, h1);
      h0 = fdot2u(wh[j].z, rv.z, h0);
      h1 = fdot2u(wh[j].w, rv.w, h1);
    }
    psH[kq][u_l] = h0 + h1;
    __syncthreads();
    if (tid < 32) {
      float sh = cgh;
#pragma unroll
      for (int k = 0; k < 8; k++) sh += psH[k][tid];
      const float hh = tanh_fast(sh);
      const float z = zbuf[tid];
      const float hn = z * hown[tid] + (1.f - z) * hh;
      out[((size_t)bb * NT + gt) * NU + u] = hn;
      hown[tid] = hn;
      const float hnn = __shfl_down(hn, 1);
      if ((tid & 1) == 0) {
        const uint32_t pk = packh2(hn, hnn);
        h2full[s * 16 + (tid >> 1)] = pk;
        __hip_atomic_store(&exB[tid >> 1], ((u64)tickB << 32) | pk,
                           __ATOMIC_RELAXED, __HIP_MEMORY_SCOPE_AGENT);
      }
      cgz = ngz;
      cgr = ngr;
      cgh = ngh;
    }
    __syncthreads();
    // gather siblings' h slices
    if (tid < 128) {
      const int which = tid >> 4, w = tid & 15;
      if (which != s) {
        const u64* p = exch + 4096 + ((size_t)bb * 8 + which) * 16 + w;
        u64 v;
        do {
          v = __hip_atomic_load(p, __ATOMIC_RELAXED, __HIP_MEMORY_SCOPE_AGENT);
        } while ((uint32_t)(v >> 32) < tickB);
        h2full[which * 16 + w] = (uint32_t)v;
      }
    }
    __syncthreads();
  }
  if (tid < 32) hstate[bb * NU + s * 32 + tid] = hown[tid];
}

extern "C" void kernel_launch(void* const* d_in, const int* in_sizes, int n_in,
                              void* d_out, int out_size, void* d_ws, size_t ws_size,
                              hipStream_t stream) {
  (void)in_sizes; (void)n_in; (void)out_size;
  const float* x = (const float*)d_in[0];
  const float* Wz = (const float*)d_in[1];
  const float* Wr = (const float*)d_in[2];
  const float* Wh = (const float*)d_in[3];
  float* out = (float*)d_out;

  // ws layout: [Gh segT*48KB] [Wp 384KB] [exch 64KB] [hstate 32KB]
  const size_t fixedBytes = 393216 + 65536 + 32768 + 4096;
  size_t usable = (ws_size > fixedBytes) ? ws_size - fixedBytes : 0;
  int segT = (int)(usable / 49152);  // 49152 B of G per timestep
  segT = (segT / 128) * 128;
  if (segT > NT) segT = NT;
  if (segT < 128) segT = 128;  // ws known >= 51 MB from prior rounds

  char* wsb = (char*)d_ws;
  __half* Gh = (__half*)wsb;
  uint32_t* Wp = (uint32_t*)(wsb + (size_t)segT * 49152);
  u64* exch = (u64*)(wsb + (size_t)segT * 49152 + 393216);
  float* hstate = (float*)(wsb + (size_t)segT * 49152 + 393216 + 65536);

  gru_prep<<<448, 256, 0, stream>>>(Wz, Wr, Wh, Wp, (uint32_t*)exch);

  for (int t0 = 0; t0 < NT; t0 += segT) {
    const int ntt = (NT - t0 < segT) ? (NT - t0) : segT;
    gru_gemm<<<(NB * ntt / 128) * 12, 512, 0, stream>>>(x, Wz, Wr, Wh, Gh, t0, ntt);
    gru_rec<<<256, 256, 0, stream>>>(Wp, Gh, out, exch, hstate, t0, ntt,
                                     (t0 == 0) ? 1 : 0);
  }
}